// Round 4
// baseline (301.864 us; speedup 1.0000x reference)
//
#include <hip/hip_runtime.h>
#include <hip/hip_bf16.h>

typedef __attribute__((ext_vector_type(8))) short short8;
typedef __attribute__((ext_vector_type(4))) float f32x4;

#define NPROTO 64
#define DIM    512
#define TAU_INV 5.0f

__device__ __forceinline__ unsigned short f2bf(float f) {
    union { float f; unsigned int u; } v; v.f = f;
    unsigned int r = v.u + 0x7FFFu + ((v.u >> 16) & 1u);  // round-to-nearest-even
    return (unsigned short)(r >> 16);
}

// ---------------------------------------------------------------------------
// Prep: p_norm (normalized protos, bf16, [64][512]) and protos^T (raw, bf16,
// [512][64]).
// ---------------------------------------------------------------------------
__global__ void pb_prep(const float* __restrict__ protos,
                        unsigned short* __restrict__ pnorm,
                        unsigned short* __restrict__ protosT) {
    const int k    = blockIdx.x;
    const int lane = threadIdx.x;
    const float* row = protos + k * DIM;
    float x[8];
    float ss = 0.0f;
#pragma unroll
    for (int j = 0; j < 8; ++j) {
        x[j] = row[lane * 8 + j];
        ss += x[j] * x[j];
    }
#pragma unroll
    for (int m = 1; m < 64; m <<= 1) ss += __shfl_xor(ss, m, 64);
    const float s = 1.0f / fmaxf(sqrtf(ss), 1e-12f);
    short8 pn;
#pragma unroll
    for (int j = 0; j < 8; ++j) pn[j] = (short)f2bf(x[j] * s);
    *reinterpret_cast<short8*>(pnorm + k * DIM + lane * 8) = pn;
#pragma unroll
    for (int j = 0; j < 8; ++j)
        protosT[(lane * 8 + j) * NPROTO + k] = f2bf(x[j]);
}

// ---------------------------------------------------------------------------
// K1: logits = (z_raw · p_norm^T) * (5/|z|), softmax -> store w + logits.
// Read-dominated streaming kernel (256 MB R, 64 MB W). 32 rows/wave,
// register A-prefetch 1 step ahead (v2 structure). No LDS.
// ---------------------------------------------------------------------------
__global__ __launch_bounds__(256, 4) void pb_logits(
    const float* __restrict__ seg,
    const unsigned short* __restrict__ pnorm,    // [64][512] bf16
    float* __restrict__ out_w,                   // [N][64]
    float* __restrict__ out_log) {               // [N][64]

    const int wid  = (int)(threadIdx.x >> 6);
    const int lane = (int)(threadIdx.x & 63);
    const int g    = lane >> 4;
    const int r16  = lane & 15;
    const long n0  = ((long)blockIdx.x * 4 + wid) * 32;

    f32x4 acc0[4] = {}, acc1[4] = {};
    float ss0 = 0.0f, ss1 = 0.0f;
    const float* ap0 = seg + (n0 + r16) * DIM + g * 8;
    const float* ap1 = ap0 + 16 * DIM;

    f32x4 a00 = *reinterpret_cast<const f32x4*>(ap0);
    f32x4 a01 = *reinterpret_cast<const f32x4*>(ap0 + 4);
    f32x4 a10 = *reinterpret_cast<const f32x4*>(ap1);
    f32x4 a11 = *reinterpret_cast<const f32x4*>(ap1 + 4);

#pragma unroll
    for (int kt = 0; kt < 16; ++kt) {
        f32x4 n00, n01, n10, n11;
        if (kt < 15) {
            n00 = *reinterpret_cast<const f32x4*>(ap0 + (kt + 1) * 32);
            n01 = *reinterpret_cast<const f32x4*>(ap0 + (kt + 1) * 32 + 4);
            n10 = *reinterpret_cast<const f32x4*>(ap1 + (kt + 1) * 32);
            n11 = *reinterpret_cast<const f32x4*>(ap1 + (kt + 1) * 32 + 4);
        }
        short8 af0, af1;
#pragma unroll
        for (int j = 0; j < 4; ++j) {
            ss0 += a00[j] * a00[j] + a01[j] * a01[j];
            ss1 += a10[j] * a10[j] + a11[j] * a11[j];
            af0[j] = (short)f2bf(a00[j]); af0[j + 4] = (short)f2bf(a01[j]);
            af1[j] = (short)f2bf(a10[j]); af1[j + 4] = (short)f2bf(a11[j]);
        }
        const unsigned short* bbase = pnorm + r16 * DIM + g * 8 + kt * 32;
#pragma unroll
        for (int c = 0; c < 4; ++c) {
            const short8 bf = *reinterpret_cast<const short8*>(bbase + c * 16 * DIM);
            acc0[c] = __builtin_amdgcn_mfma_f32_16x16x32_bf16(af0, bf, acc0[c], 0, 0, 0);
            acc1[c] = __builtin_amdgcn_mfma_f32_16x16x32_bf16(af1, bf, acc1[c], 0, 0, 0);
        }
        if (kt < 15) { a00 = n00; a01 = n01; a10 = n10; a11 = n11; }
    }

    ss0 += __shfl_xor(ss0, 16, 64); ss0 += __shfl_xor(ss0, 32, 64);
    ss1 += __shfl_xor(ss1, 16, 64); ss1 += __shfl_xor(ss1, 32, 64);
    const float sco0 = TAU_INV / fmaxf(sqrtf(ss0), 1e-12f);
    const float sco1 = TAU_INV / fmaxf(sqrtf(ss1), 1e-12f);
    float sc0[4], sc1[4];
#pragma unroll
    for (int q = 0; q < 4; ++q) {
        sc0[q] = __shfl(sco0, g * 4 + q, 64);
        sc1[q] = __shfl(sco1, g * 4 + q, 64);
    }

    float lg0[4][4], lg1[4][4];
#pragma unroll
    for (int c = 0; c < 4; ++c)
#pragma unroll
        for (int q = 0; q < 4; ++q) {
            lg0[c][q] = acc0[c][q] * sc0[q];
            lg1[c][q] = acc1[c][q] * sc1[q];
            out_log[(n0 + g * 4 + q) * NPROTO + c * 16 + r16]      = lg0[c][q];
            out_log[(n0 + 16 + g * 4 + q) * NPROTO + c * 16 + r16] = lg1[c][q];
        }

    float w0[4][4], w1[4][4];
#pragma unroll
    for (int q = 0; q < 4; ++q) {
        float mx0 = fmaxf(fmaxf(lg0[0][q], lg0[1][q]), fmaxf(lg0[2][q], lg0[3][q]));
        float mx1 = fmaxf(fmaxf(lg1[0][q], lg1[1][q]), fmaxf(lg1[2][q], lg1[3][q]));
#pragma unroll
        for (int msk = 1; msk < 16; msk <<= 1) {
            mx0 = fmaxf(mx0, __shfl_xor(mx0, msk, 64));
            mx1 = fmaxf(mx1, __shfl_xor(mx1, msk, 64));
        }
        float e0[4], e1[4], sum0 = 0.0f, sum1 = 0.0f;
#pragma unroll
        for (int c = 0; c < 4; ++c) {
            e0[c] = __expf(lg0[c][q] - mx0); sum0 += e0[c];
            e1[c] = __expf(lg1[c][q] - mx1); sum1 += e1[c];
        }
#pragma unroll
        for (int msk = 1; msk < 16; msk <<= 1) {
            sum0 += __shfl_xor(sum0, msk, 64);
            sum1 += __shfl_xor(sum1, msk, 64);
        }
        const float i0 = 1.0f / sum0, i1 = 1.0f / sum1;
#pragma unroll
        for (int c = 0; c < 4; ++c) { w0[c][q] = e0[c] * i0; w1[c][q] = e1[c] * i1; }
    }

#pragma unroll
    for (int c = 0; c < 4; ++c)
#pragma unroll
        for (int q = 0; q < 4; ++q) {
            out_w[(n0 + g * 4 + q) * NPROTO + c * 16 + r16]      = w0[c][q];
            out_w[(n0 + 16 + g * 4 + q) * NPROTO + c * 16 + r16] = w1[c][q];
        }
}

// ---------------------------------------------------------------------------
// K2: pattern = w · protos. Write-dominated (32 MB R stream + 256 MB W).
// w tile (32 rows x 64) loaded coalesced (1KB/instr), converted to bf16,
// transposed to MFMA A-layout via a wave-private XOR-swizzled LDS tile
// (no __syncthreads -- each wave owns its slice; lgkmcnt orders within wave).
// ---------------------------------------------------------------------------
__global__ __launch_bounds__(256, 4) void pb_pattern(
    const float* __restrict__ w,                 // [N][64]
    const unsigned short* __restrict__ protosT,  // [512][64] bf16
    float* __restrict__ out_pat) {               // [N][512]

    __shared__ unsigned short wbuf_all[4 * 2 * 16 * 64];  // 16KB

    const int wid  = (int)(threadIdx.x >> 6);
    const int lane = (int)(threadIdx.x & 63);
    const int g    = lane >> 4;
    const int r16  = lane & 15;
    const long n0  = ((long)blockIdx.x * 4 + wid) * 32;

    unsigned short* wb = wbuf_all + wid * 2048;  // frag f at +f*1024 elems

    // coalesced w load: instr i reads 1KB; lane covers row i*4+(lane>>4),
    // cols (lane&15)*4 .. +3. Write 8B to swizzled LDS A-layout.
    const float* wsrc = w + n0 * NPROTO;
#pragma unroll
    for (int i = 0; i < 8; ++i) {
        const f32x4 v = *reinterpret_cast<const f32x4*>(wsrc + i * 256 + lane * 4);
        const int row  = i * 4 + (lane >> 4);   // 0..31
        const int frag = row >> 4;
        const int r    = row & 15;
        const int k0   = (lane & 15) * 4;
        union { unsigned short s[4]; unsigned long long u; } pk;
#pragma unroll
        for (int j = 0; j < 4; ++j) pk.s[j] = f2bf(v[j]);
        const int byte = (r * 128 + k0 * 2) ^ ((r & 7) << 4);
        *reinterpret_cast<unsigned long long*>(
            reinterpret_cast<char*>(wb + frag * 1024) + byte) = pk.u;
    }

    // read back A-fragments (wave-private; compiler inserts lgkmcnt)
    short8 wa[2][2];
    {
        const int b0 = (r16 * 128 + g * 16)      ^ ((r16 & 7) << 4);
        const int b1 = (r16 * 128 + g * 16 + 64) ^ ((r16 & 7) << 4);
#pragma unroll
        for (int f = 0; f < 2; ++f) {
            wa[f][0] = *reinterpret_cast<const short8*>(
                reinterpret_cast<char*>(wb + f * 1024) + b0);
            wa[f][1] = *reinterpret_cast<const short8*>(
                reinterpret_cast<char*>(wb + f * 1024) + b1);
        }
    }

    // pattern: K=64 (2 MFMA), 32 col-tiles, 2-deep B prefetch
    short8 pbuf[2][2];
    const unsigned short* btile = protosT + r16 * NPROTO + g * 8;
    pbuf[0][0] = *reinterpret_cast<const short8*>(btile);
    pbuf[0][1] = *reinterpret_cast<const short8*>(btile + 32);
#pragma unroll
    for (int cp = 0; cp < 32; ++cp) {
        if (cp < 31) {
            const unsigned short* bn = btile + (cp + 1) * 16 * NPROTO;
            pbuf[(cp + 1) & 1][0] = *reinterpret_cast<const short8*>(bn);
            pbuf[(cp + 1) & 1][1] = *reinterpret_cast<const short8*>(bn + 32);
        }
        f32x4 p0 = {}, p1 = {};
        p0 = __builtin_amdgcn_mfma_f32_16x16x32_bf16(wa[0][0], pbuf[cp & 1][0], p0, 0, 0, 0);
        p0 = __builtin_amdgcn_mfma_f32_16x16x32_bf16(wa[0][1], pbuf[cp & 1][1], p0, 0, 0, 0);
        p1 = __builtin_amdgcn_mfma_f32_16x16x32_bf16(wa[1][0], pbuf[cp & 1][0], p1, 0, 0, 0);
        p1 = __builtin_amdgcn_mfma_f32_16x16x32_bf16(wa[1][1], pbuf[cp & 1][1], p1, 0, 0, 0);
#pragma unroll
        for (int q = 0; q < 4; ++q) {
            out_pat[(n0 + g * 4 + q) * DIM + cp * 16 + r16]      = p0[q];
            out_pat[(n0 + 16 + g * 4 + q) * DIM + cp * 16 + r16] = p1[q];
        }
    }
}

extern "C" void kernel_launch(void* const* d_in, const int* in_sizes, int n_in,
                              void* d_out, int out_size, void* d_ws, size_t ws_size,
                              hipStream_t stream) {
    const float* seg    = (const float*)d_in[0];
    const float* protos = (const float*)d_in[1];
    const int N = in_sizes[0] / DIM;  // 131072

    float* out     = (float*)d_out;
    float* out_pat = out;
    float* out_w   = out_pat + (size_t)N * DIM;
    float* out_log = out_w + (size_t)N * NPROTO;

    unsigned short* pnorm   = (unsigned short*)d_ws;
    unsigned short* protosT = pnorm + NPROTO * DIM;

    pb_prep<<<NPROTO, 64, 0, stream>>>(protos, pnorm, protosT);
    pb_logits<<<N / 128, 256, 0, stream>>>(seg, pnorm, out_w, out_log);
    pb_pattern<<<N / 128, 256, 0, stream>>>(out_w, protosT, out_pat);
}

// Round 5
// 186.535 us; speedup vs baseline: 1.6183x; 1.6183x over previous
//
#include <hip/hip_runtime.h>
#include <hip/hip_bf16.h>

typedef __attribute__((ext_vector_type(8))) short short8;
typedef __attribute__((ext_vector_type(4))) float f32x4;

#define NPROTO 64
#define DIM    512
#define TAU_INV 5.0f

__device__ __forceinline__ unsigned short f2bf(float f) {
    union { float f; unsigned int u; } v; v.f = f;
    unsigned int r = v.u + 0x7FFFu + ((v.u >> 16) & 1u);  // round-to-nearest-even
    return (unsigned short)(r >> 16);
}

// ---------------------------------------------------------------------------
// Prep: p_norm (normalized protos, bf16, [64][512]) and protos^T (raw, bf16,
// [512][64]). Cached (we WANT these L2/L3 resident).
// ---------------------------------------------------------------------------
__global__ void pb_prep(const float* __restrict__ protos,
                        unsigned short* __restrict__ pnorm,
                        unsigned short* __restrict__ protosT) {
    const int k    = blockIdx.x;
    const int lane = threadIdx.x;
    const float* row = protos + k * DIM;
    float x[8];
    float ss = 0.0f;
#pragma unroll
    for (int j = 0; j < 8; ++j) {
        x[j] = row[lane * 8 + j];
        ss += x[j] * x[j];
    }
#pragma unroll
    for (int m = 1; m < 64; m <<= 1) ss += __shfl_xor(ss, m, 64);
    const float s = 1.0f / fmaxf(sqrtf(ss), 1e-12f);
    short8 pn;
#pragma unroll
    for (int j = 0; j < 8; ++j) pn[j] = (short)f2bf(x[j] * s);
    *reinterpret_cast<short8*>(pnorm + k * DIM + lane * 8) = pn;
#pragma unroll
    for (int j = 0; j < 8; ++j)
        protosT[(lane * 8 + j) * NPROTO + k] = f2bf(x[j]);
}

// ---------------------------------------------------------------------------
// Fused main v5: v2 structure (32 rows/wave, fused logits+softmax+pattern),
// but: NT loads on seg, NT stores on all outputs (keep streams out of L3),
// 2-wave/128-thread blocks (8 blocks/CU -> tail backfill), XCD swizzle,
// no __syncthreads (wave-private LDS transpose, proven in v4 pb_pattern).
// ---------------------------------------------------------------------------
__global__ __launch_bounds__(128, 4) void pb_main(
    const float* __restrict__ seg,
    const unsigned short* __restrict__ pnorm,    // [64][512] bf16
    const unsigned short* __restrict__ protosT,  // [512][64] bf16
    float* __restrict__ out_pat,                 // [N][512]
    float* __restrict__ out_w,                   // [N][64]
    float* __restrict__ out_log) {               // [N][64]

    __shared__ unsigned short wbuf_all[2 * 2 * 16 * 64];  // 8KB/block

    const int wid  = (int)(threadIdx.x >> 6);
    const int lane = (int)(threadIdx.x & 63);
    const int g    = lane >> 4;
    const int r16  = lane & 15;

    // bijective XCD swizzle (gridDim.x % 8 == 0)
    const int nwg  = (int)gridDim.x;
    const int cpx  = nwg >> 3;
    const int blk  = ((int)blockIdx.x & 7) * cpx + ((int)blockIdx.x >> 3);
    const long n0  = ((long)blk * 2 + wid) * 32;  // wave's first row

    // ---------------- logits matmul: K=512, 2 row-frags x 4 col-tiles --------
    f32x4 acc0[4] = {}, acc1[4] = {};
    float ss0 = 0.0f, ss1 = 0.0f;
    const float* ap0 = seg + (n0 + r16) * DIM + g * 8;
    const float* ap1 = ap0 + 16 * DIM;

    f32x4 a00 = __builtin_nontemporal_load(reinterpret_cast<const f32x4*>(ap0));
    f32x4 a01 = __builtin_nontemporal_load(reinterpret_cast<const f32x4*>(ap0 + 4));
    f32x4 a10 = __builtin_nontemporal_load(reinterpret_cast<const f32x4*>(ap1));
    f32x4 a11 = __builtin_nontemporal_load(reinterpret_cast<const f32x4*>(ap1 + 4));

#pragma unroll
    for (int kt = 0; kt < 16; ++kt) {
        f32x4 n00, n01, n10, n11;
        if (kt < 15) {
            n00 = __builtin_nontemporal_load(reinterpret_cast<const f32x4*>(ap0 + (kt + 1) * 32));
            n01 = __builtin_nontemporal_load(reinterpret_cast<const f32x4*>(ap0 + (kt + 1) * 32 + 4));
            n10 = __builtin_nontemporal_load(reinterpret_cast<const f32x4*>(ap1 + (kt + 1) * 32));
            n11 = __builtin_nontemporal_load(reinterpret_cast<const f32x4*>(ap1 + (kt + 1) * 32 + 4));
        }
        short8 af0, af1;
#pragma unroll
        for (int j = 0; j < 4; ++j) {
            ss0 += a00[j] * a00[j] + a01[j] * a01[j];
            ss1 += a10[j] * a10[j] + a11[j] * a11[j];
            af0[j] = (short)f2bf(a00[j]); af0[j + 4] = (short)f2bf(a01[j]);
            af1[j] = (short)f2bf(a10[j]); af1[j + 4] = (short)f2bf(a11[j]);
        }
        const unsigned short* bbase = pnorm + r16 * DIM + g * 8 + kt * 32;
#pragma unroll
        for (int c = 0; c < 4; ++c) {
            const short8 bf = *reinterpret_cast<const short8*>(bbase + c * 16 * DIM);
            acc0[c] = __builtin_amdgcn_mfma_f32_16x16x32_bf16(af0, bf, acc0[c], 0, 0, 0);
            acc1[c] = __builtin_amdgcn_mfma_f32_16x16x32_bf16(af1, bf, acc1[c], 0, 0, 0);
        }
        if (kt < 15) { a00 = n00; a01 = n01; a10 = n10; a11 = n11; }
    }

    // ---- per-row 1/|z|, redistribute to D-layout rows ---------------------
    ss0 += __shfl_xor(ss0, 16, 64); ss0 += __shfl_xor(ss0, 32, 64);
    ss1 += __shfl_xor(ss1, 16, 64); ss1 += __shfl_xor(ss1, 32, 64);
    const float sco0 = TAU_INV / fmaxf(sqrtf(ss0), 1e-12f);
    const float sco1 = TAU_INV / fmaxf(sqrtf(ss1), 1e-12f);
    float sc0[4], sc1[4];
#pragma unroll
    for (int q = 0; q < 4; ++q) {
        sc0[q] = __shfl(sco0, g * 4 + q, 64);
        sc1[q] = __shfl(sco1, g * 4 + q, 64);
    }

    float lg0[4][4], lg1[4][4];
#pragma unroll
    for (int c = 0; c < 4; ++c)
#pragma unroll
        for (int q = 0; q < 4; ++q) {
            lg0[c][q] = acc0[c][q] * sc0[q];
            lg1[c][q] = acc1[c][q] * sc1[q];
            __builtin_nontemporal_store(lg0[c][q],
                &out_log[(n0 + g * 4 + q) * NPROTO + c * 16 + r16]);
            __builtin_nontemporal_store(lg1[c][q],
                &out_log[(n0 + 16 + g * 4 + q) * NPROTO + c * 16 + r16]);
        }

    // ---- softmax over 64 protos per row -----------------------------------
    float w0[4][4], w1[4][4];
#pragma unroll
    for (int q = 0; q < 4; ++q) {
        float mx0 = fmaxf(fmaxf(lg0[0][q], lg0[1][q]), fmaxf(lg0[2][q], lg0[3][q]));
        float mx1 = fmaxf(fmaxf(lg1[0][q], lg1[1][q]), fmaxf(lg1[2][q], lg1[3][q]));
#pragma unroll
        for (int msk = 1; msk < 16; msk <<= 1) {
            mx0 = fmaxf(mx0, __shfl_xor(mx0, msk, 64));
            mx1 = fmaxf(mx1, __shfl_xor(mx1, msk, 64));
        }
        float e0[4], e1[4], sum0 = 0.0f, sum1 = 0.0f;
#pragma unroll
        for (int c = 0; c < 4; ++c) {
            e0[c] = __expf(lg0[c][q] - mx0); sum0 += e0[c];
            e1[c] = __expf(lg1[c][q] - mx1); sum1 += e1[c];
        }
#pragma unroll
        for (int msk = 1; msk < 16; msk <<= 1) {
            sum0 += __shfl_xor(sum0, msk, 64);
            sum1 += __shfl_xor(sum1, msk, 64);
        }
        const float i0 = 1.0f / sum0, i1 = 1.0f / sum1;
#pragma unroll
        for (int c = 0; c < 4; ++c) { w0[c][q] = e0[c] * i0; w1[c][q] = e1[c] * i1; }
    }

    // ---- store w (NT) + wave-private LDS transpose (XOR swizzled) ---------
    unsigned short* wb0 = wbuf_all + (wid * 2 + 0) * 1024;
    unsigned short* wb1 = wbuf_all + (wid * 2 + 1) * 1024;
#pragma unroll
    for (int c = 0; c < 4; ++c)
#pragma unroll
        for (int q = 0; q < 4; ++q) {
            __builtin_nontemporal_store(w0[c][q],
                &out_w[(n0 + g * 4 + q) * NPROTO + c * 16 + r16]);
            __builtin_nontemporal_store(w1[c][q],
                &out_w[(n0 + 16 + g * 4 + q) * NPROTO + c * 16 + r16]);
            const int row  = g * 4 + q;
            const int col  = c * 16 + r16;
            const int byte = (row * 128 + col * 2) ^ ((row & 7) << 4);
            *reinterpret_cast<unsigned short*>(reinterpret_cast<char*>(wb0) + byte) = f2bf(w0[c][q]);
            *reinterpret_cast<unsigned short*>(reinterpret_cast<char*>(wb1) + byte) = f2bf(w1[c][q]);
        }

    // wave-private read-back (compiler orders via lgkmcnt; no barrier needed)
    short8 wa[2][2];
    {
        const int b0 = (r16 * 128 + g * 16)      ^ ((r16 & 7) << 4);
        const int b1 = (r16 * 128 + g * 16 + 64) ^ ((r16 & 7) << 4);
        wa[0][0] = *reinterpret_cast<const short8*>(reinterpret_cast<char*>(wb0) + b0);
        wa[0][1] = *reinterpret_cast<const short8*>(reinterpret_cast<char*>(wb0) + b1);
        wa[1][0] = *reinterpret_cast<const short8*>(reinterpret_cast<char*>(wb1) + b0);
        wa[1][1] = *reinterpret_cast<const short8*>(reinterpret_cast<char*>(wb1) + b1);
    }

    // ---- pattern = w · protos : K=64, 32 col-tiles, 2-deep B prefetch -----
    short8 pbuf[2][2];
    const unsigned short* btile = protosT + r16 * NPROTO + g * 8;
    pbuf[0][0] = *reinterpret_cast<const short8*>(btile);
    pbuf[0][1] = *reinterpret_cast<const short8*>(btile + 32);
#pragma unroll
    for (int cp = 0; cp < 32; ++cp) {
        if (cp < 31) {
            const unsigned short* bn = btile + (cp + 1) * 16 * NPROTO;
            pbuf[(cp + 1) & 1][0] = *reinterpret_cast<const short8*>(bn);
            pbuf[(cp + 1) & 1][1] = *reinterpret_cast<const short8*>(bn + 32);
        }
        f32x4 p0 = {}, p1 = {};
        p0 = __builtin_amdgcn_mfma_f32_16x16x32_bf16(wa[0][0], pbuf[cp & 1][0], p0, 0, 0, 0);
        p0 = __builtin_amdgcn_mfma_f32_16x16x32_bf16(wa[0][1], pbuf[cp & 1][1], p0, 0, 0, 0);
        p1 = __builtin_amdgcn_mfma_f32_16x16x32_bf16(wa[1][0], pbuf[cp & 1][0], p1, 0, 0, 0);
        p1 = __builtin_amdgcn_mfma_f32_16x16x32_bf16(wa[1][1], pbuf[cp & 1][1], p1, 0, 0, 0);
#pragma unroll
        for (int q = 0; q < 4; ++q) {
            __builtin_nontemporal_store(p0[q],
                &out_pat[(n0 + g * 4 + q) * DIM + cp * 16 + r16]);
            __builtin_nontemporal_store(p1[q],
                &out_pat[(n0 + 16 + g * 4 + q) * DIM + cp * 16 + r16]);
        }
    }
}

extern "C" void kernel_launch(void* const* d_in, const int* in_sizes, int n_in,
                              void* d_out, int out_size, void* d_ws, size_t ws_size,
                              hipStream_t stream) {
    const float* seg    = (const float*)d_in[0];
    const float* protos = (const float*)d_in[1];
    const int N = in_sizes[0] / DIM;  // 131072

    float* out     = (float*)d_out;
    float* out_pat = out;
    float* out_w   = out_pat + (size_t)N * DIM;
    float* out_log = out_w + (size_t)N * NPROTO;

    unsigned short* pnorm   = (unsigned short*)d_ws;
    unsigned short* protosT = pnorm + NPROTO * DIM;

    pb_prep<<<NPROTO, 64, 0, stream>>>(protos, pnorm, protosT);
    pb_main<<<N / 64, 128, 0, stream>>>(seg, pnorm, protosT, out_pat, out_w, out_log);
}